// Round 19
// baseline (64.981 us; speedup 1.0000x reference)
//
#include <hip/hip_runtime.h>

#define B_ 8192
#define T_ 128
#define I_ 28
#define H_ 64
#define O_ 10
#define RING 8
#define SLOTF 512   // floats per x-ring slot: 448 data + 64 pad
#define HS 72       // ushort stride per batch-row in h buffer (144 B, 16B-aligned)

typedef __attribute__((ext_vector_type(8))) short bf16x8;
typedef __attribute__((ext_vector_type(4))) float f32x4;
typedef __attribute__((ext_vector_type(4))) unsigned int u32x4;

__device__ __forceinline__ unsigned short f2bf(float f) {
    unsigned int u = __builtin_bit_cast(unsigned int, f);
    u += 0x7fffu + ((u >> 16) & 1u);   // RNE
    return (unsigned short)(u >> 16);
}
__device__ __forceinline__ unsigned int cvtpk(float lo, float hi) {
    unsigned int r;
    asm("v_cvt_pk_bf16_f32 %0, %1, %2" : "=v"(r) : "v"(lo), "v"(hi));
    return r;
}
__device__ __forceinline__ bf16x8 mkfrag(unsigned int a, unsigned int b,
                                         unsigned int c, unsigned int d) {
    u32x4 u = {a, b, c, d};
    return __builtin_bit_cast(bf16x8, u);
}
__device__ __forceinline__ float exp2f_fast(float x) {
#if __has_builtin(__builtin_amdgcn_exp2f)
    return __builtin_amdgcn_exp2f(x);
#else
    return __expf(x * 0.6931471805599453f);
#endif
}
// tanh pair -> packed bf16x2. tanh(x)=1-2/(1+2^(2*log2e*x)); saturates at +-1.
__device__ __forceinline__ unsigned int tanh2_bf(float xa, float xb) {
    float ta = exp2f_fast(xa * 2.885390081777927f);
    float tb = exp2f_fast(xb * 2.885390081777927f);
    float ra = __builtin_amdgcn_rcpf(1.0f + ta);
    float rb = __builtin_amdgcn_rcpf(1.0f + tb);
    return cvtpk(fmaf(-2.0f, ra, 1.0f), fmaf(-2.0f, rb, 1.0f));
}

// async global->LDS: no VGPR destination (no regalloc hazard); counted by vmcnt
__device__ __forceinline__ void gload_lds(const float* g, float* l) {
    __builtin_amdgcn_global_load_lds(
        (const __attribute__((address_space(1))) unsigned int*)g,
        (__attribute__((address_space(3))) unsigned int*)l, 16, 0, 0);
}

#define MFMA(A, B, C) __builtin_amdgcn_mfma_f32_16x16x32_bf16((A), (B), (C), 0, 0, 0)

__launch_bounds__(128, 1)
__global__ void rnn_split2_kernel(const float* __restrict__ x,
                                  const float* __restrict__ W_ih,
                                  const float* __restrict__ W_hh,
                                  const float* __restrict__ b_ih,
                                  const float* __restrict__ b_hh,
                                  const float* __restrict__ W_out,
                                  const float* __restrict__ b_out,
                                  float* __restrict__ out) {
    __shared__ __align__(16) float xs[RING][SLOTF];
    __shared__ __align__(16) unsigned short hb[2][16 * HS];

    const int tid = threadIdx.x;
    const int lane = tid & 63;
    const int w = tid >> 6;           // wave id (0,1) -- owns tiles {2w, 2w+1}
    const int m = lane & 15;          // batch row within tile
    const int g = lane >> 4;          // k-group
    const int b0 = blockIdx.x * 16;
    const int row = b0 + m;

    // Swapped-operand MFMA + permuted-W (verified R3/R5-R18), H split 2 ways:
    // tile t computes h-cols n_phys(t,i)=8*(i>>2)+4*(t&1)+(i&3)+32*(t>>1).
    // Wave w owns t=2w (cols 8g+r+32w) and t=2w+1 (cols 8g+4+r+32w): the 8
    // outputs per lane are CONTIGUOUS -> ONE b128 LDS write per step.
    bf16x8 wih0, wih1, whhA0, whhA1, whhB0, whhB1;
    f32x4 biasC0, biasC1;
#pragma unroll
    for (int tt = 0; tt < 2; ++tt) {
        const int t = 2 * w + tt;
        const int nA = 8 * (m >> 2) + 4 * (t & 1) + (m & 3) + 32 * (t >> 1);
        bf16x8 wi, wa, wb;
#pragma unroll
        for (int j = 0; j < 8; ++j) {
            const int k = 8 * g + j;
            wi[j] = (k < I_) ? (short)f2bf(W_ih[nA * I_ + k]) : (short)0;
            wa[j] = (short)f2bf(W_hh[nA * H_ + k]);
            wb[j] = (short)f2bf(W_hh[nA * H_ + 32 + k]);
        }
        f32x4 bc;
#pragma unroll
        for (int r = 0; r < 4; ++r) {
            const int nb = 8 * g + 4 * (t & 1) + r + 32 * (t >> 1);
            bc[r] = b_ih[nb] + b_hh[nb];
        }
        if (tt == 0) { wih0 = wi; whhA0 = wa; whhB0 = wb; biasC0 = bc; }
        else         { wih1 = wi; whhA1 = wa; whhB1 = wb; biasC1 = bc; }
    }
    const int wbase = m * HS + 8 * g + 32 * w;   // h write base (8 ushorts, 16B aligned)
    const int rbase = m * HS + 8 * g;            // h frag read base

    // ---- x staging: slot = 16 rows x 112B (7 x 16B chunks/row). ONLY wave 0
    // issues DMA; wave 1 inherits completion via w0's vmcnt + s_barrier.
    const int cA = lane;
    const int cB = (64 + lane <= 111) ? (64 + lane) : 111;
    const float* gA = x + (size_t)(b0 + cA / 7) * (T_ * I_) + (cA % 7) * 4;
    const float* gB = x + (size_t)(b0 + cB / 7) * (T_ * I_) + (cB % 7) * 4;

#define ISSUE(s, tt) do {                                                    \
        const int tc_ = ((tt) < T_) ? (tt) : (T_ - 1);                       \
        gload_lds(gA + (size_t)tc_ * I_, &xs[s][0]);                         \
        gload_lds(gB + (size_t)tc_ * I_, &xs[s][256]);                       \
    } while (0)

    const int xoff = m * 28 + g * 8;
    const int hoff = (g < 3) ? 4 : 0;   // g==3 hi half = k 28..31 (zero weights)

#define XFRAG(s, dst) do {                                                   \
        const f32x4 lo_ = *reinterpret_cast<const f32x4*>(&xs[s][xoff]);     \
        const f32x4 hi_ = *reinterpret_cast<const f32x4*>(&xs[s][xoff + hoff]); \
        dst = mkfrag(cvtpk(lo_[0], lo_[1]), cvtpk(lo_[2], lo_[3]),           \
                     cvtpk(hi_[0], hi_[1]), cvtpk(hi_[2], hi_[3]));          \
    } while (0)

    // Drain setup VMEM so w0's vmcnt counts only staging DMA from here on.
    __builtin_amdgcn_sched_barrier(0);
    asm volatile("s_waitcnt vmcnt(0)" ::: "memory");
    __builtin_amdgcn_sched_barrier(0);

    if (w == 0) {
        ISSUE(0, 0); ISSUE(1, 1); ISSUE(2, 2); ISSUE(3, 3);
        ISSUE(4, 4); ISSUE(5, 5); ISSUE(6, 6); ISSUE(7, 7);
        // slots 0,1,2 landed when <=10 of the 16 remain outstanding
        asm volatile("s_waitcnt vmcnt(10)" ::: "memory");
    }
    asm volatile("s_barrier" ::: "memory");   // publish x slots 0..2

    f32x4 pxA0, pxA1, pxB0, pxB1;   // px pipelined ONE step ahead (off-chain)
    {
        bf16x8 xf0; XFRAG(0, xf0);
        pxA0 = MFMA(wih0, xf0, biasC0);       // px(t=0), both tiles
        pxA1 = MFMA(wih1, xf0, biasC1);
    }
    bf16x8 h0f = mkfrag(0, 0, 0, 0), h1f = mkfrag(0, 0, 0, 0);

    // Body for time t (u=t%8; PXC*/PXN* = px(t)/px(t+1) per tile) -- R11
    // order, 2-wave: XFRAG+2 px-MFMA at top (off-chain); per tile chained
    // recA->recB (tiles parallel); 4x tanh2 -> ONE b128 write; w0 DMA+vmcnt;
    // lgkm drain + barrier; read next full-H frags.
#define STEP(u, TB, PXC0, PXC1, PXN0, PXN1) do {                              \
        bf16x8 xf; XFRAG(((u) + 1) & 7, xf);                                  \
        PXN0 = MFMA(wih0, xf, biasC0);                                        \
        PXN1 = MFMA(wih1, xf, biasC1);                                        \
        f32x4 a0 = MFMA(whhA0, h0f, PXC0);                                    \
        a0 = MFMA(whhB0, h1f, a0);                                            \
        f32x4 a1 = MFMA(whhA1, h0f, PXC1);                                    \
        a1 = MFMA(whhB1, h1f, a1);                                            \
        u32x4 pv;                                                             \
        pv[0] = tanh2_bf(a0[0], a0[1]);                                       \
        pv[1] = tanh2_bf(a0[2], a0[3]);                                       \
        pv[2] = tanh2_bf(a1[0], a1[1]);                                       \
        pv[3] = tanh2_bf(a1[2], a1[3]);                                       \
        *reinterpret_cast<u32x4*>(&hb[((u) + 1) & 1][wbase]) = pv;            \
        if (w == 0) {                                                         \
            ISSUE((u), (TB) + (u) + 8);                                       \
            asm volatile("s_waitcnt vmcnt(10)" ::: "memory");                 \
        }                                                                     \
        asm volatile("s_waitcnt lgkmcnt(0)\n\ts_barrier" ::: "memory");       \
        h0f = *reinterpret_cast<const bf16x8*>(&hb[((u) + 1) & 1][rbase]);    \
        h1f = *reinterpret_cast<const bf16x8*>(&hb[((u) + 1) & 1][rbase + 32]); \
    } while (0)

    for (int tb = 0; tb < T_; tb += 8) {
        STEP(0, tb, pxA0, pxA1, pxB0, pxB1); STEP(1, tb, pxB0, pxB1, pxA0, pxA1);
        STEP(2, tb, pxA0, pxA1, pxB0, pxB1); STEP(3, tb, pxB0, pxB1, pxA0, pxA1);
        STEP(4, tb, pxA0, pxA1, pxB0, pxB1); STEP(5, tb, pxB0, pxB1, pxA0, pxA1);
        STEP(6, tb, pxA0, pxA1, pxB0, pxB1); STEP(7, tb, pxB0, pxB1, pxA0, pxA1);
    }
#undef STEP
#undef XFRAG
#undef ISSUE

    // ---- epilogue: out[row][o] = h_last . W_out[o] + b_out[o] ----
    // Both waves hold identical h_last frags; wave 0 does the output.
    if (w == 0) {
        float hf[16];
        {
            u32x4 H0 = __builtin_bit_cast(u32x4, h0f);
            u32x4 H1 = __builtin_bit_cast(u32x4, h1f);
#pragma unroll
            for (int p = 0; p < 4; ++p) {
                hf[2 * p]     = __builtin_bit_cast(float, H0[p] << 16);
                hf[2 * p + 1] = __builtin_bit_cast(float, H0[p] & 0xffff0000u);
                hf[8 + 2 * p]     = __builtin_bit_cast(float, H1[p] << 16);
                hf[8 + 2 * p + 1] = __builtin_bit_cast(float, H1[p] & 0xffff0000u);
            }
        }
        float pacc[O_];
#pragma unroll
        for (int o = 0; o < O_; ++o) {
            const float* wo = W_out + o * H_;
            float4 wA = *reinterpret_cast<const float4*>(wo + 8 * g);
            float4 wB = *reinterpret_cast<const float4*>(wo + 8 * g + 4);
            float4 wC = *reinterpret_cast<const float4*>(wo + 32 + 8 * g);
            float4 wD = *reinterpret_cast<const float4*>(wo + 32 + 8 * g + 4);
            float s = hf[0] * wA.x + hf[1] * wA.y + hf[2] * wA.z + hf[3] * wA.w
                    + hf[4] * wB.x + hf[5] * wB.y + hf[6] * wB.z + hf[7] * wB.w
                    + hf[8] * wC.x + hf[9] * wC.y + hf[10] * wC.z + hf[11] * wC.w
                    + hf[12] * wD.x + hf[13] * wD.y + hf[14] * wD.z + hf[15] * wD.w;
            s += __shfl_xor(s, 16);
            s += __shfl_xor(s, 32);
            pacc[o] = s;
        }
        if (g == 0) {
#pragma unroll
            for (int o = 0; o < O_; ++o)
                out[(size_t)row * O_ + o] = pacc[o] + b_out[o];
        }
    }
}

extern "C" void kernel_launch(void* const* d_in, const int* in_sizes, int n_in,
                              void* d_out, int out_size, void* d_ws, size_t ws_size,
                              hipStream_t stream) {
    const float* x     = (const float*)d_in[0];
    const float* W_ih  = (const float*)d_in[1];
    const float* W_hh  = (const float*)d_in[2];
    const float* b_ih  = (const float*)d_in[3];
    const float* b_hh  = (const float*)d_in[4];
    const float* W_out = (const float*)d_in[5];
    const float* b_out = (const float*)d_in[6];
    float* out = (float*)d_out;

    dim3 grid(B_ / 16);
    dim3 block(128);
    rnn_split2_kernel<<<grid, block, 0, stream>>>(x, W_ih, W_hh, b_ih, b_hh,
                                                  W_out, b_out, out);
}

// Round 20
// 45.021 us; speedup vs baseline: 1.4434x; 1.4434x over previous
//
#include <hip/hip_runtime.h>

#define B_ 8192
#define T_ 128
#define I_ 28
#define H_ 64
#define O_ 10
#define RING 8
#define SLOTF 512   // floats per x-ring slot: 448 data + 64 pad
#define HS 72       // ushort stride per batch-row in h buffer (144 B, 16B-aligned)

typedef __attribute__((ext_vector_type(8))) short bf16x8;
typedef __attribute__((ext_vector_type(4))) float f32x4;
typedef __attribute__((ext_vector_type(4))) unsigned int u32x4;

__device__ __forceinline__ unsigned short f2bf(float f) {
    unsigned int u = __builtin_bit_cast(unsigned int, f);
    u += 0x7fffu + ((u >> 16) & 1u);   // RNE
    return (unsigned short)(u >> 16);
}
__device__ __forceinline__ unsigned int cvtpk(float lo, float hi) {
    unsigned int r;
    asm("v_cvt_pk_bf16_f32 %0, %1, %2" : "=v"(r) : "v"(lo), "v"(hi));
    return r;
}
__device__ __forceinline__ bf16x8 mkfrag(unsigned int a, unsigned int b,
                                         unsigned int c, unsigned int d) {
    u32x4 u = {a, b, c, d};
    return __builtin_bit_cast(bf16x8, u);
}
__device__ __forceinline__ float exp2f_fast(float x) {
#if __has_builtin(__builtin_amdgcn_exp2f)
    return __builtin_amdgcn_exp2f(x);
#else
    return __expf(x * 0.6931471805599453f);
#endif
}
// tanh pair -> packed bf16x2. tanh(x)=1-2/(1+2^(2*log2e*x)); saturates at +-1.
__device__ __forceinline__ unsigned int tanh2_bf(float xa, float xb) {
    float ta = exp2f_fast(xa * 2.885390081777927f);
    float tb = exp2f_fast(xb * 2.885390081777927f);
    float ra = __builtin_amdgcn_rcpf(1.0f + ta);
    float rb = __builtin_amdgcn_rcpf(1.0f + tb);
    return cvtpk(fmaf(-2.0f, ra, 1.0f), fmaf(-2.0f, rb, 1.0f));
}

// async global->LDS: no VGPR destination (no regalloc hazard); counted by vmcnt
__device__ __forceinline__ void gload_lds(const float* g, float* l) {
    __builtin_amdgcn_global_load_lds(
        (const __attribute__((address_space(1))) unsigned int*)g,
        (__attribute__((address_space(3))) unsigned int*)l, 16, 0, 0);
}

#define MFMA(A, B, C) __builtin_amdgcn_mfma_f32_16x16x32_bf16((A), (B), (C), 0, 0, 0)

__launch_bounds__(256, 1)
__global__ void rnn_split_kernel(const float* __restrict__ x,
                                 const float* __restrict__ W_ih,
                                 const float* __restrict__ W_hh,
                                 const float* __restrict__ b_ih,
                                 const float* __restrict__ b_hh,
                                 const float* __restrict__ W_out,
                                 const float* __restrict__ b_out,
                                 float* __restrict__ out) {
    __shared__ __align__(16) float xs[RING][SLOTF];
    __shared__ __align__(16) unsigned short hb[2][16 * HS];

    const int tid = threadIdx.x;
    const int lane = tid & 63;
    const int w = tid >> 6;           // wave id == output tile (h cols, permuted)
    const int m = lane & 15;          // batch row within tile
    const int g = lane >> 4;          // k-group
    const int b0 = blockIdx.x * 16;
    const int row = b0 + m;

    // Swapped-operand MFMA + permuted-W (verified R3/R5-R19), H split 4 ways:
    // wave w computes h-cols n_phys(w,i)=8*(i>>2)+4*(w&1)+(i&3)+32*(w>>1).
    // Lane(g,m) reg r yields n=8g+4(w&1)+r+32(w>>1): 4 CONTIGUOUS cols ->
    // one b64 LDS write; every wave then b128-reads its full-H B-fragments.
    bf16x8 wih, whhA, whhB;
    f32x4 biasC;
    {
        const int nA = 8 * (m >> 2) + 4 * (w & 1) + (m & 3) + 32 * (w >> 1);
#pragma unroll
        for (int j = 0; j < 8; ++j) {
            const int k = 8 * g + j;
            wih[j]  = (k < I_) ? (short)f2bf(W_ih[nA * I_ + k]) : (short)0;
            whhA[j] = (short)f2bf(W_hh[nA * H_ + k]);
            whhB[j] = (short)f2bf(W_hh[nA * H_ + 32 + k]);
        }
#pragma unroll
        for (int r = 0; r < 4; ++r) {
            const int nb = 8 * g + 4 * (w & 1) + r + 32 * (w >> 1);
            biasC[r] = b_ih[nb] + b_hh[nb];
        }
    }
    const int wbase = m * HS + 8 * g + 4 * (w & 1) + 32 * (w >> 1);  // h write (ushorts)
    const int rbase = m * HS + 8 * g;                                 // h frag read

    // ---- x staging: slot = 16 rows x 112B (7 x 16B chunks/row). ONLY wave 0
    // issues DMA; other waves inherit completion via w0's vmcnt + s_barrier.
    const int cA = lane;
    const int cB = (64 + lane <= 111) ? (64 + lane) : 111;
    const float* gA = x + (size_t)(b0 + cA / 7) * (T_ * I_) + (cA % 7) * 4;
    const float* gB = x + (size_t)(b0 + cB / 7) * (T_ * I_) + (cB % 7) * 4;

#define ISSUE(s, tt) do {                                                    \
        const int tc_ = ((tt) < T_) ? (tt) : (T_ - 1);                       \
        gload_lds(gA + (size_t)tc_ * I_, &xs[s][0]);                         \
        gload_lds(gB + (size_t)tc_ * I_, &xs[s][256]);                       \
    } while (0)

    const int xoff = m * 28 + g * 8;
    const int hoff = (g < 3) ? 4 : 0;   // g==3 hi half = k 28..31 (zero weights)

#define XFRAG(s, dst) do {                                                   \
        const f32x4 lo_ = *reinterpret_cast<const f32x4*>(&xs[s][xoff]);     \
        const f32x4 hi_ = *reinterpret_cast<const f32x4*>(&xs[s][xoff + hoff]); \
        dst = mkfrag(cvtpk(lo_[0], lo_[1]), cvtpk(lo_[2], lo_[3]),           \
                     cvtpk(hi_[0], hi_[1]), cvtpk(hi_[2], hi_[3]));          \
    } while (0)

    // Drain setup VMEM so w0's vmcnt counts only staging DMA from here on.
    __builtin_amdgcn_sched_barrier(0);
    asm volatile("s_waitcnt vmcnt(0)" ::: "memory");
    __builtin_amdgcn_sched_barrier(0);

    if (w == 0) {
        ISSUE(0, 0); ISSUE(1, 1); ISSUE(2, 2); ISSUE(3, 3);
        ISSUE(4, 4); ISSUE(5, 5); ISSUE(6, 6); ISSUE(7, 7);
        // slots 0,1,2 landed when <=10 of the 16 remain outstanding
        asm volatile("s_waitcnt vmcnt(10)" ::: "memory");
    }
    asm volatile("s_barrier" ::: "memory");   // publish x slots 0..2

    f32x4 pxA, pxB;   // px pipelined ONE step ahead (computed early, off-chain)
    {
        bf16x8 xf0; XFRAG(0, xf0);
        pxA = MFMA(wih, xf0, biasC);          // px(t=0)
    }
    bf16x8 h0f = mkfrag(0, 0, 0, 0), h1f = mkfrag(0, 0, 0, 0);

    // Body for time t (u=t%8, PXC=px(t), PXN=px(t+1) out) -- R11 structure,
    // ONE change vs R11: REC-FIRST order. The chained rec-MFMAs issue at the
    // TOP (gated only by the h-reads from before the barrier), then XFRAG+px
    // issue UNDER the rec-MFMA latency shadow (their x-lgkm wait no longer
    // delays the chain), then tanh -> write -> w0 DMA -> barrier -> h-read.
#define STEP(u, TB, PXC, PXN) do {                                            \
        f32x4 aA = MFMA(whhA, h0f, PXC);                                      \
        aA = MFMA(whhB, h1f, aA);                                             \
        bf16x8 xf; XFRAG(((u) + 1) & 7, xf);                                  \
        PXN = MFMA(wih, xf, biasC);                                           \
        const unsigned int p0 = tanh2_bf(aA[0], aA[1]);                       \
        const unsigned int p1 = tanh2_bf(aA[2], aA[3]);                       \
        uint2 pv; pv.x = p0; pv.y = p1;                                       \
        *reinterpret_cast<uint2*>(&hb[((u) + 1) & 1][wbase]) = pv;            \
        if (w == 0) {                                                         \
            ISSUE((u), (TB) + (u) + 8);                                       \
            asm volatile("s_waitcnt vmcnt(10)" ::: "memory");                 \
        }                                                                     \
        asm volatile("s_waitcnt lgkmcnt(0)\n\ts_barrier" ::: "memory");       \
        h0f = *reinterpret_cast<const bf16x8*>(&hb[((u) + 1) & 1][rbase]);    \
        h1f = *reinterpret_cast<const bf16x8*>(&hb[((u) + 1) & 1][rbase + 32]); \
    } while (0)

    for (int tb = 0; tb < T_; tb += 8) {
        STEP(0, tb, pxA, pxB); STEP(1, tb, pxB, pxA);
        STEP(2, tb, pxA, pxB); STEP(3, tb, pxB, pxA);
        STEP(4, tb, pxA, pxB); STEP(5, tb, pxB, pxA);
        STEP(6, tb, pxA, pxB); STEP(7, tb, pxB, pxA);
    }
#undef STEP
#undef XFRAG
#undef ISSUE

    // ---- epilogue: out[row][o] = h_last . W_out[o] + b_out[o] ----
    // All waves hold identical h_last frags; wave 0 does the output.
    if (w == 0) {
        float hf[16];
        {
            u32x4 H0 = __builtin_bit_cast(u32x4, h0f);
            u32x4 H1 = __builtin_bit_cast(u32x4, h1f);
#pragma unroll
            for (int p = 0; p < 4; ++p) {
                hf[2 * p]     = __builtin_bit_cast(float, H0[p] << 16);
                hf[2 * p + 1] = __builtin_bit_cast(float, H0[p] & 0xffff0000u);
                hf[8 + 2 * p]     = __builtin_bit_cast(float, H1[p] << 16);
                hf[8 + 2 * p + 1] = __builtin_bit_cast(float, H1[p] & 0xffff0000u);
            }
        }
        float pacc[O_];
#pragma unroll
        for (int o = 0; o < O_; ++o) {
            const float* wo = W_out + o * H_;
            float4 wA = *reinterpret_cast<const float4*>(wo + 8 * g);
            float4 wB = *reinterpret_cast<const float4*>(wo + 8 * g + 4);
            float4 wC = *reinterpret_cast<const float4*>(wo + 32 + 8 * g);
            float4 wD = *reinterpret_cast<const float4*>(wo + 32 + 8 * g + 4);
            float s = hf[0] * wA.x + hf[1] * wA.y + hf[2] * wA.z + hf[3] * wA.w
                    + hf[4] * wB.x + hf[5] * wB.y + hf[6] * wB.z + hf[7] * wB.w
                    + hf[8] * wC.x + hf[9] * wC.y + hf[10] * wC.z + hf[11] * wC.w
                    + hf[12] * wD.x + hf[13] * wD.y + hf[14] * wD.z + hf[15] * wD.w;
            s += __shfl_xor(s, 16);
            s += __shfl_xor(s, 32);
            pacc[o] = s;
        }
        if (g == 0) {
#pragma unroll
            for (int o = 0; o < O_; ++o)
                out[(size_t)row * O_ + o] = pacc[o] + b_out[o];
        }
    }
}

extern "C" void kernel_launch(void* const* d_in, const int* in_sizes, int n_in,
                              void* d_out, int out_size, void* d_ws, size_t ws_size,
                              hipStream_t stream) {
    const float* x     = (const float*)d_in[0];
    const float* W_ih  = (const float*)d_in[1];
    const float* W_hh  = (const float*)d_in[2];
    const float* b_ih  = (const float*)d_in[3];
    const float* b_hh  = (const float*)d_in[4];
    const float* W_out = (const float*)d_in[5];
    const float* b_out = (const float*)d_in[6];
    float* out = (float*)d_out;

    dim3 grid(B_ / 16);
    dim3 block(256);
    rnn_split_kernel<<<grid, block, 0, stream>>>(x, W_ih, W_hh, b_ih, b_hh,
                                                 W_out, b_out, out);
}